// Round 1
// baseline (782.618 us; speedup 1.0000x reference)
//
#include <hip/hip_runtime.h>
#include <math.h>

#define N_NODES 50000
#define N_EDGES 800000
#define HEADS 8
#define DHEAD 8
#define CLAMP_V 5.0f

// ---------------- Kernel 1: Q/K/V node projections ----------------
// Q[n,c] = sum_k x[n,k]*WQ[k,c] + bQ[c]   (64x64 GEMMs, W cached in L1/L2)
// Block 256 threads: lane c = t&63, wave nl = t>>6; 16 nodes per block.
__global__ __launch_bounds__(256) void qkv_kernel(
    const float* __restrict__ x,
    const float* __restrict__ WQ, const float* __restrict__ bQ,
    const float* __restrict__ WK, const float* __restrict__ bK,
    const float* __restrict__ WV, const float* __restrict__ bV,
    float* __restrict__ Q, float* __restrict__ K, float* __restrict__ V)
{
    const int t = threadIdx.x;
    const int c = t & 63;
    const int nl = t >> 6;     // wave id 0..3
    const int base = blockIdx.x * 16;

    float accQ[4], accK[4], accV[4];
    int nodes[4];
#pragma unroll
    for (int j = 0; j < 4; ++j) {
        nodes[j] = base + j * 4 + nl;   // 3125*16 = 50000 exactly, no tail
        accQ[j] = bQ[c]; accK[j] = bK[c]; accV[j] = bV[c];
    }
    for (int k = 0; k < 64; ++k) {
        const float wq = WQ[k * 64 + c];
        const float wk = WK[k * 64 + c];
        const float wv = WV[k * 64 + c];
#pragma unroll
        for (int j = 0; j < 4; ++j) {
            const float xv = x[nodes[j] * 64 + k];   // broadcast within wave
            accQ[j] += xv * wq;
            accK[j] += xv * wk;
            accV[j] += xv * wv;
        }
    }
#pragma unroll
    for (int j = 0; j < 4; ++j) {
        const int n = nodes[j];
        Q[n * 64 + c] = accQ[j];
        K[n * 64 + c] = accK[j];
        V[n * 64 + c] = accV[j];
    }
}

// ---------------- Kernel 2: per-edge E-GEMM + score + denom ----------------
// Per edge e: E[0..127] = edge_attr[e]@WE + bE
//   e_t[h,k] = signsqrt((K[src]+Q[dst])[h,k] * E[h*16+k]) + E[h*16+8+k]
//   wE[e] = e_t ; logit[h] = clip(sum_k e_t*Aw[k,h]) ; denom[dst,h] += exp(logit)
// Each wave processes 4 edges per iteration (register-blocks the E-GEMM so
// each WE LDS read feeds 4 FMAs -> cuts LDS traffic 4x).
__global__ __launch_bounds__(256) void edge_kernel(
    const float* __restrict__ edge_attr,
    const int* __restrict__ src_idx, const int* __restrict__ dst_idx,
    const float* __restrict__ WE, const float* __restrict__ bE,
    const float* __restrict__ Aw,
    const float* __restrict__ Qn, const float* __restrict__ Kn,
    float* __restrict__ wE_out, float* __restrict__ denom)
{
    __shared__ float WEs[64 * 128];      // 32 KB
    __shared__ float bEs[128];
    __shared__ float Aws[64];
    __shared__ float eas[4][4 * 64];     // [wave][edge j][k]   4 KB
    __shared__ float Es [4][4 * 128];    // [wave][edge j][col] 8 KB

    const int t = threadIdx.x;
    for (int i = t; i < 64 * 128; i += 256) WEs[i] = WE[i];
    if (t < 128) bEs[t] = bE[t];
    if (t < 64)  Aws[t] = Aw[t];
    __syncthreads();

    const int wave = t >> 6;
    const int lane = t & 63;
    const int h = lane >> 3;
    const int kk = lane & 7;

    const int perIter = gridDim.x * 16;                 // 16 edges per block-iter
    const int iters = (N_EDGES + perIter - 1) / perIter;

    for (int it = 0; it < iters; ++it) {
        const int ebase = (it * gridDim.x + blockIdx.x) * 16 + wave * 4;

        // stage 4 edge_attr rows per wave
#pragma unroll
        for (int j = 0; j < 4; ++j) {
            const int e = ebase + j;
            float v = 0.f;
            if (e < N_EDGES) v = edge_attr[e * 64 + lane];
            eas[wave][j * 64 + lane] = v;
        }
        __syncthreads();

        // E-GEMM: thread computes cols (2*lane, 2*lane+1) for 4 edges
        float acc0[4], acc1[4];
#pragma unroll
        for (int j = 0; j < 4; ++j) { acc0[j] = bEs[2 * lane]; acc1[j] = bEs[2 * lane + 1]; }
        for (int k = 0; k < 64; ++k) {
            const float2 w = reinterpret_cast<const float2*>(WEs)[k * 64 + lane];
#pragma unroll
            for (int j = 0; j < 4; ++j) {
                const float a = eas[wave][j * 64 + k];   // LDS broadcast
                acc0[j] += a * w.x;
                acc1[j] += a * w.y;
            }
        }
#pragma unroll
        for (int j = 0; j < 4; ++j) {
            reinterpret_cast<float2*>(Es[wave])[j * 64 + lane] = make_float2(acc0[j], acc1[j]);
        }
        __syncthreads();

        // score phase: lane = h*8+kk handles one (h,k) per edge
#pragma unroll
        for (int j = 0; j < 4; ++j) {
            const int e = ebase + j;
            if (e >= N_EDGES) continue;
            const int s = src_idx[e];
            const int d = dst_idx[e];
            const float kq = Kn[s * 64 + lane] + Qn[d * 64 + lane];
            const float ew = Es[wave][j * 128 + h * 16 + kk];
            const float eb = Es[wave][j * 128 + h * 16 + 8 + kk];
            float sc = kq * ew;
            sc = copysignf(sqrtf(fabsf(sc)), sc) + eb;   // sqrt(relu(x))-sqrt(relu(-x))
            wE_out[e * 64 + lane] = sc;

            float p = sc * Aws[kk * 8 + h];
            p += __shfl_xor(p, 1);
            p += __shfl_xor(p, 2);
            p += __shfl_xor(p, 4);
            p = fminf(fmaxf(p, -CLAMP_V), CLAMP_V);
            const float ex = __expf(p);
            if (kk == 0) unsafeAtomicAdd(&denom[d * 8 + h], ex);
        }
        __syncthreads();   // protect eas/Es before next iteration overwrites
    }
}

// ---------------- Kernel 3: scatter wV ----------------
// Per edge: attn = exp(logit)/denom[dst]; wV[dst] += attn*(V[src] + e_t@VeRow)
// (folds the rowV@VeRow term per-edge: linearity of segment_sum)
__global__ __launch_bounds__(256) void scatter_kernel(
    const int* __restrict__ src_idx, const int* __restrict__ dst_idx,
    const float* __restrict__ Vn, const float* __restrict__ wE_out,
    const float* __restrict__ denom,
    const float* __restrict__ Aw, const float* __restrict__ VeRow,
    float* __restrict__ wV_out)
{
    __shared__ float VeL[512];
    __shared__ float AwL[64];
    const int t = threadIdx.x;
    if (t < 64) AwL[t] = Aw[t];
    for (int i = t; i < 512; i += 256) VeL[i] = VeRow[i];
    __syncthreads();

    const int wave = t >> 6;
    const int lane = t & 63;
    const int h = lane >> 3;
    const int kk = lane & 7;
    const int totalWaves = gridDim.x * 4;

    for (int e = blockIdx.x * 4 + wave; e < N_EDGES; e += totalWaves) {
        const int s = src_idx[e];
        const int d = dst_idx[e];
        const float et = wE_out[e * 64 + lane];

        // recompute logit/ex exactly as kernel 2 did (bitwise identical ops)
        float p = et * AwL[kk * 8 + h];
        p += __shfl_xor(p, 1);
        p += __shfl_xor(p, 2);
        p += __shfl_xor(p, 4);
        p = fminf(fmaxf(p, -CLAMP_V), CLAMP_V);
        const float ex = __expf(p);
        const float dn = denom[d * 8 + h];
        const float attn = ex / (dn + 1e-16f);

        const float vv = Vn[s * 64 + lane];
        float rsum = 0.f;
#pragma unroll
        for (int dd = 0; dd < 8; ++dd) {
            const float etd = __shfl(et, (lane & 56) + dd);   // e_t[h,dd]
            rsum += etd * VeL[dd * 64 + lane];                // VeRow[dd,h,kk]
        }
        unsafeAtomicAdd(&wV_out[d * 64 + lane], attn * (vv + rsum));
    }
}

extern "C" void kernel_launch(void* const* d_in, const int* in_sizes, int n_in,
                              void* d_out, int out_size, void* d_ws, size_t ws_size,
                              hipStream_t stream) {
    const float* x         = (const float*)d_in[0];
    const float* edge_attr = (const float*)d_in[1];
    const int*   ei        = (const int*)  d_in[2];
    const float* WQ = (const float*)d_in[3];
    const float* bQ = (const float*)d_in[4];
    const float* WK = (const float*)d_in[5];
    const float* bK = (const float*)d_in[6];
    const float* WE = (const float*)d_in[7];
    const float* bE = (const float*)d_in[8];
    const float* WV = (const float*)d_in[9];
    const float* bV = (const float*)d_in[10];
    const float* Aw = (const float*)d_in[11];
    const float* VeRow = (const float*)d_in[12];

    float* out    = (float*)d_out;
    float* wV_out = out;                       // 50000*64 floats
    float* wE_out = out + (size_t)N_NODES * 64; // 800000*64 floats

    float* ws    = (float*)d_ws;
    float* Q     = ws;                          // 3.2M floats
    float* K     = ws + 3200000;                // 3.2M
    float* V     = ws + 6400000;                // 3.2M
    float* denom = ws + 9600000;                // 400000 floats (50000*8)

    const int* src_idx = ei;
    const int* dst_idx = ei + N_EDGES;

    hipMemsetAsync(wV_out, 0, (size_t)N_NODES * 64 * sizeof(float), stream);
    hipMemsetAsync(denom, 0, (size_t)N_NODES * 8 * sizeof(float), stream);

    qkv_kernel<<<3125, 256, 0, stream>>>(x, WQ, bQ, WK, bK, WV, bV, Q, K, V);
    edge_kernel<<<2048, 256, 0, stream>>>(edge_attr, src_idx, dst_idx, WE, bE, Aw,
                                          Q, K, wE_out, denom);
    scatter_kernel<<<2048, 256, 0, stream>>>(src_idx, dst_idx, V, wE_out, denom,
                                             Aw, VeRow, wV_out);
}

// Round 2
// 648.468 us; speedup vs baseline: 1.2069x; 1.2069x over previous
//
#include <hip/hip_runtime.h>
#include <hip/hip_bf16.h>
#include <math.h>

#define N_NODES 50000
#define N_EDGES 800000
#define HEADS 8
#define DHEAD 8
#define CLAMP_V 5.0f

typedef short short8 __attribute__((ext_vector_type(8)));
typedef float f32x4  __attribute__((ext_vector_type(4)));

static __device__ inline short f2bf(float x) {
    __hip_bfloat16 h = __float2bfloat16(x);   // RNE
    return __builtin_bit_cast(short, h);
}
static __device__ inline float bf2f(short s) {
    unsigned u = ((unsigned)(unsigned short)s) << 16;
    return __builtin_bit_cast(float, u);
}

// ---------------- Kernel 1: Q/K/V node projections (unchanged) ----------------
__global__ __launch_bounds__(256) void qkv_kernel(
    const float* __restrict__ x,
    const float* __restrict__ WQ, const float* __restrict__ bQ,
    const float* __restrict__ WK, const float* __restrict__ bK,
    const float* __restrict__ WV, const float* __restrict__ bV,
    float* __restrict__ Q, float* __restrict__ K, float* __restrict__ V)
{
    const int t = threadIdx.x;
    const int c = t & 63;
    const int nl = t >> 6;
    const int base = blockIdx.x * 16;

    float accQ[4], accK[4], accV[4];
    int nodes[4];
#pragma unroll
    for (int j = 0; j < 4; ++j) {
        nodes[j] = base + j * 4 + nl;
        accQ[j] = bQ[c]; accK[j] = bK[c]; accV[j] = bV[c];
    }
    for (int k = 0; k < 64; ++k) {
        const float wq = WQ[k * 64 + c];
        const float wk = WK[k * 64 + c];
        const float wv = WV[k * 64 + c];
#pragma unroll
        for (int j = 0; j < 4; ++j) {
            const float xv = x[nodes[j] * 64 + k];
            accQ[j] += xv * wq;
            accK[j] += xv * wk;
            accV[j] += xv * wv;
        }
    }
#pragma unroll
    for (int j = 0; j < 4; ++j) {
        const int n = nodes[j];
        Q[n * 64 + c] = accQ[j];
        K[n * 64 + c] = accK[j];
        V[n * 64 + c] = accV[j];
    }
}

// ---------------- Kernel 2: MFMA E-GEMM + score + denom ----------------
// E = edge_attr @ WE + bE via bf16 split-precision MFMA (3 products:
// a_hi*w_hi + a_lo*w_hi + a_hi*w_lo; residual ~2^-18 rel).
// Per block-iter: 64 edges (16 per wave). No barriers in the main loop —
// all LDS regions are wave-private (A fragments, E score buffer); B
// fragments are read-only after the single init barrier.
//
// mfma_f32_16x16x32_bf16 layout assumption (per cdna4 guide m89/m91):
//   A: lane holds A[row = lane&15][k = (lane>>4)*8 + j],  j=0..7
//   B: lane holds B[k = (lane>>4)*8 + j][col = lane&15]
//   C/D: col = lane&15, row = (lane>>4)*4 + reg
__global__ __launch_bounds__(256) void edge_kernel(
    const float* __restrict__ edge_attr,
    const int* __restrict__ src_idx, const int* __restrict__ dst_idx,
    const float* __restrict__ WE, const float* __restrict__ bE,
    const float* __restrict__ Aw,
    const float* __restrict__ Qn, const float* __restrict__ Kn,
    float* __restrict__ wE_out, float* __restrict__ denom)
{
    // raw layout: [0,16K)=B_hi  [16K,32K)=B_lo  [32K,48K)=A frags (4KB/wave)
    //             [48K,56K)=E score buf (2KB/wave)
    __shared__ __align__(16) char raw[57344];
    __shared__ float bEs[128];
    __shared__ float Aws[64];

    short8* Bhi = (short8*)raw;                  // [(ct*2+kh)*64 + lane]
    short8* Blo = (short8*)(raw + 16384);

    const int t = threadIdx.x;
    const int wave = t >> 6;
    const int lane = t & 63;

    // ---- init: build bf16 hi/lo B-fragments straight from global WE (L2-hot)
    short* BhiE = (short*)raw;
    short* BloE = (short*)(raw + 16384);
    for (int i = t; i < 8192; i += 256) {
        const int j  = i & 7;
        const int ln = (i >> 3) & 63;
        const int kh = (i >> 9) & 1;
        const int ct = i >> 10;
        const int k   = kh * 32 + ((ln >> 4) << 3) + j;
        const int col = (ct << 4) + (ln & 15);
        const float w = WE[k * 128 + col];
        const short hb = f2bf(w);
        BhiE[i] = hb;
        BloE[i] = f2bf(w - bf2f(hb));
    }
    if (t < 128) bEs[t] = bE[t];
    if (t < 64)  Aws[t] = Aw[t];
    __syncthreads();

    short8* Ahi_w  = (short8*)(raw + 32768 + wave * 4096);          // [kh*64+lane]
    short8* Alo_w  = (short8*)(raw + 32768 + wave * 4096 + 2048);
    float*  Ebuf_w = (float*) (raw + 49152 + wave * 2048);          // [col*4 + rr]

    const int h  = lane >> 3;
    const int kk = lane & 7;
    const int g  = lane >> 4;

    for (int it = blockIdx.x; it < 12500; it += gridDim.x) {
        const int ebase = it * 64 + wave * 16;

        // ---- stage A: 16 edges x 64 k as bf16 hi/lo fragments
        // thread (lane) pass p handles kh=p, frag-lane=lane:
        //   rows lane&15, k = p*32 + (lane>>4)*8 + 0..7  (2 coalesced float4)
#pragma unroll
        for (int p = 0; p < 2; ++p) {
            const float* src = edge_attr
                + (size_t)(ebase + (lane & 15)) * 64 + p * 32 + ((lane >> 4) << 3);
            const float4 u = *(const float4*)src;
            const float4 v = *(const float4*)(src + 4);
            const float xv[8] = {u.x, u.y, u.z, u.w, v.x, v.y, v.z, v.w};
            short8 hi, lo;
#pragma unroll
            for (int j = 0; j < 8; ++j) {
                const short hb = f2bf(xv[j]);
                hi[j] = hb;
                lo[j] = f2bf(xv[j] - bf2f(hb));
            }
            Ahi_w[p * 64 + lane] = hi;    // contiguous 16B/lane: conflict-free
            Alo_w[p * 64 + lane] = lo;
        }

        // ---- MFMA: acc[ct] = E[16 rows][ct*16..+15]
        f32x4 acc[8] = {};
#pragma unroll
        for (int kh = 0; kh < 2; ++kh) {
            const short8 ah = Ahi_w[kh * 64 + lane];
            const short8 al = Alo_w[kh * 64 + lane];
#pragma unroll
            for (int ct = 0; ct < 8; ++ct) {
                const short8 bh = Bhi[(ct * 2 + kh) * 64 + lane];
                const short8 bl = Blo[(ct * 2 + kh) * 64 + lane];
                acc[ct] = __builtin_amdgcn_mfma_f32_16x16x32_bf16(ah, bh, acc[ct], 0, 0, 0);
                acc[ct] = __builtin_amdgcn_mfma_f32_16x16x32_bf16(al, bh, acc[ct], 0, 0, 0);
                acc[ct] = __builtin_amdgcn_mfma_f32_16x16x32_bf16(ah, bl, acc[ct], 0, 0, 0);
            }
        }

        // ---- score phase: 4 quarters of 4 edges (reuse 2KB E buffer)
        // quarter q rows q*4..q*4+3 live in lanes with g==q, regs rr=0..3.
#pragma unroll
        for (int q = 0; q < 4; ++q) {
            if (g == q) {
#pragma unroll
                for (int ct = 0; ct < 8; ++ct) {
                    const int col = (ct << 4) + (lane & 15);
                    const float b = bEs[col];
                    f32x4 vq = acc[ct];
                    vq[0] += b; vq[1] += b; vq[2] += b; vq[3] += b;
                    *(f32x4*)(Ebuf_w + col * 4) = vq;   // E^T[col][rr]
                }
            }
            __asm__ volatile("s_waitcnt lgkmcnt(0)" ::: "memory");
#pragma unroll
            for (int rr = 0; rr < 4; ++rr) {
                const int e = ebase + q * 4 + rr;
                const int s = src_idx[e];      // wave-uniform -> s_load
                const int d = dst_idx[e];
                const float kq = Kn[(size_t)s * 64 + lane] + Qn[(size_t)d * 64 + lane];
                const float ew = Ebuf_w[(h * 16 + kk) * 4 + rr];
                const float eb = Ebuf_w[(h * 16 + kk + 8) * 4 + rr];
                float sc = kq * ew;
                sc = copysignf(sqrtf(fabsf(sc)), sc) + eb;  // signed sqrt
                wE_out[(size_t)e * 64 + lane] = sc;

                float pp = sc * Aws[kk * 8 + h];
                pp += __shfl_xor(pp, 1);
                pp += __shfl_xor(pp, 2);
                pp += __shfl_xor(pp, 4);
                pp = fminf(fmaxf(pp, -CLAMP_V), CLAMP_V);
                const float ex = __expf(pp);
                if (kk == 0) unsafeAtomicAdd(&denom[(size_t)d * 8 + h], ex);
            }
        }
    }
}

// ---------------- Kernel 3: scatter wV (unchanged) ----------------
__global__ __launch_bounds__(256) void scatter_kernel(
    const int* __restrict__ src_idx, const int* __restrict__ dst_idx,
    const float* __restrict__ Vn, const float* __restrict__ wE_out,
    const float* __restrict__ denom,
    const float* __restrict__ Aw, const float* __restrict__ VeRow,
    float* __restrict__ wV_out)
{
    __shared__ float VeL[512];
    __shared__ float AwL[64];
    const int t = threadIdx.x;
    if (t < 64) AwL[t] = Aw[t];
    for (int i = t; i < 512; i += 256) VeL[i] = VeRow[i];
    __syncthreads();

    const int wave = t >> 6;
    const int lane = t & 63;
    const int h = lane >> 3;
    const int kk = lane & 7;
    const int totalWaves = gridDim.x * 4;

    for (int e = blockIdx.x * 4 + wave; e < N_EDGES; e += totalWaves) {
        const int s = src_idx[e];
        const int d = dst_idx[e];
        const float et = wE_out[(size_t)e * 64 + lane];

        float p = et * AwL[kk * 8 + h];
        p += __shfl_xor(p, 1);
        p += __shfl_xor(p, 2);
        p += __shfl_xor(p, 4);
        p = fminf(fmaxf(p, -CLAMP_V), CLAMP_V);
        const float ex = __expf(p);
        const float dn = denom[(size_t)d * 8 + h];
        const float attn = ex / (dn + 1e-16f);

        const float vv = Vn[(size_t)s * 64 + lane];
        float rsum = 0.f;
#pragma unroll
        for (int dd = 0; dd < 8; ++dd) {
            const float etd = __shfl(et, (lane & 56) + dd);
            rsum += etd * VeL[dd * 64 + lane];
        }
        unsafeAtomicAdd(&wV_out[(size_t)d * 64 + lane], attn * (vv + rsum));
    }
}

extern "C" void kernel_launch(void* const* d_in, const int* in_sizes, int n_in,
                              void* d_out, int out_size, void* d_ws, size_t ws_size,
                              hipStream_t stream) {
    const float* x         = (const float*)d_in[0];
    const float* edge_attr = (const float*)d_in[1];
    const int*   ei        = (const int*)  d_in[2];
    const float* WQ = (const float*)d_in[3];
    const float* bQ = (const float*)d_in[4];
    const float* WK = (const float*)d_in[5];
    const float* bK = (const float*)d_in[6];
    const float* WE = (const float*)d_in[7];
    const float* bE = (const float*)d_in[8];
    const float* WV = (const float*)d_in[9];
    const float* bV = (const float*)d_in[10];
    const float* Aw = (const float*)d_in[11];
    const float* VeRow = (const float*)d_in[12];

    float* out    = (float*)d_out;
    float* wV_out = out;                        // 50000*64
    float* wE_out = out + (size_t)N_NODES * 64; // 800000*64

    float* ws    = (float*)d_ws;
    float* Q     = ws;
    float* K     = ws + 3200000;
    float* V     = ws + 6400000;
    float* denom = ws + 9600000;

    const int* src_idx = ei;
    const int* dst_idx = ei + N_EDGES;

    hipMemsetAsync(wV_out, 0, (size_t)N_NODES * 64 * sizeof(float), stream);
    hipMemsetAsync(denom, 0, (size_t)N_NODES * 8 * sizeof(float), stream);

    qkv_kernel<<<3125, 256, 0, stream>>>(x, WQ, bQ, WK, bK, WV, bV, Q, K, V);
    edge_kernel<<<512, 256, 0, stream>>>(edge_attr, src_idx, dst_idx, WE, bE, Aw,
                                         Q, K, wE_out, denom);
    scatter_kernel<<<2048, 256, 0, stream>>>(src_idx, dst_idx, V, wE_out, denom,
                                             Aw, VeRow, wV_out);
}

// Round 4
// 394.385 us; speedup vs baseline: 1.9844x; 1.6443x over previous
//
#include <hip/hip_runtime.h>
#include <hip/hip_bf16.h>
#include <math.h>

#define N_NODES 50000
#define N_EDGES 800000
#define CLAMP_V 5.0f

typedef short short8 __attribute__((ext_vector_type(8)));
typedef float f32x4  __attribute__((ext_vector_type(4)));

static __device__ inline short f2bf(float x) {
    __hip_bfloat16 h = __float2bfloat16(x);   // RNE
    return __builtin_bit_cast(short, h);
}
static __device__ inline float bf2f(short s) {
    unsigned u = ((unsigned)(unsigned short)s) << 16;
    return __builtin_bit_cast(float, u);
}

// ---------------- Kernel 1: Q/K/V node projections (unchanged, proven) ----------------
__global__ __launch_bounds__(256) void qkv_kernel(
    const float* __restrict__ x,
    const float* __restrict__ WQ, const float* __restrict__ bQ,
    const float* __restrict__ WK, const float* __restrict__ bK,
    const float* __restrict__ WV, const float* __restrict__ bV,
    float* __restrict__ Q, float* __restrict__ K, float* __restrict__ V)
{
    const int t = threadIdx.x;
    const int c = t & 63;
    const int nl = t >> 6;
    const int base = blockIdx.x * 16;

    float accQ[4], accK[4], accV[4];
    int nodes[4];
#pragma unroll
    for (int j = 0; j < 4; ++j) {
        nodes[j] = base + j * 4 + nl;
        accQ[j] = bQ[c]; accK[j] = bK[c]; accV[j] = bV[c];
    }
    for (int k = 0; k < 64; ++k) {
        const float wq = WQ[k * 64 + c];
        const float wk = WK[k * 64 + c];
        const float wv = WV[k * 64 + c];
#pragma unroll
        for (int j = 0; j < 4; ++j) {
            const float xv = x[nodes[j] * 64 + k];
            accQ[j] += xv * wq;
            accK[j] += xv * wk;
            accV[j] += xv * wv;
        }
    }
#pragma unroll
    for (int j = 0; j < 4; ++j) {
        const int n = nodes[j];
        Q[n * 64 + c] = accQ[j];
        K[n * 64 + c] = accK[j];
        V[n * 64 + c] = accV[j];
    }
}

// ---------------- Kernel 2: MFMA E-GEMM + score + denom ----------------
// R2's proven quarter-fenced transpose structure, plus correctness-neutral
// latency fixes: A fragments built directly in registers; edge indices via
// scalar loads; ALL 16 K/Q gathers issued at iteration top (after A loads)
// so they land under the MFMA phase. LDS 41KB -> 3 blocks/CU.
__global__ __launch_bounds__(256, 3) void edge_kernel(
    const float* __restrict__ edge_attr,
    const int* __restrict__ src_idx, const int* __restrict__ dst_idx,
    const float* __restrict__ WE, const float* __restrict__ bE,
    const float* __restrict__ Aw,
    const float* __restrict__ Qn, const float* __restrict__ Kn,
    float* __restrict__ wE_out, float* __restrict__ denom)
{
    // [0,16K)=B_hi  [16K,32K)=B_lo  [32K,40K)=E transpose buf (2KB/wave)
    __shared__ __align__(16) char raw[40960];
    __shared__ float bEs[128];
    __shared__ float Aws[64];

    short8* Bhi = (short8*)raw;                  // [(ct*2+kh)*64 + lane]
    short8* Blo = (short8*)(raw + 16384);

    const int t = threadIdx.x;
    const int wave = t >> 6;
    const int lane = t & 63;

    // ---- init: bf16 hi/lo B-fragments from global WE
    short* BhiE = (short*)raw;
    short* BloE = (short*)(raw + 16384);
    for (int i = t; i < 8192; i += 256) {
        const int j  = i & 7;
        const int ln = (i >> 3) & 63;
        const int kh = (i >> 9) & 1;
        const int ct = i >> 10;
        const int k   = kh * 32 + ((ln >> 4) << 3) + j;
        const int col = (ct << 4) + (ln & 15);
        const float w = WE[k * 128 + col];
        const short hb = f2bf(w);
        BhiE[i] = hb;
        BloE[i] = f2bf(w - bf2f(hb));
    }
    if (t < 128) bEs[t] = bE[t];
    if (t < 64)  Aws[t] = Aw[t];
    __syncthreads();

    float* Ebuf_w = (float*)(raw + 32768 + wave * 2048);  // [col*4 + rr]

    const int h    = lane >> 3;
    const int kk   = lane & 7;
    const int g    = lane >> 4;
    const int c4   = lane & 15;
    const int h16k = (h << 4) + kk;

    for (int it = blockIdx.x; it < 12500; it += gridDim.x) {
        const int ebase = __builtin_amdgcn_readfirstlane(it * 64 + wave * 16);

        // ---- scalar index loads for this wave's 16 edges
        int se[16], de[16];
#pragma unroll
        for (int r = 0; r < 16; ++r) {
            se[r] = src_idx[ebase + r];
            de[r] = dst_idx[ebase + r];
        }

        // ---- A fragments straight into registers (issue A loads FIRST so
        // the MFMA's vmcnt wait doesn't drain the gathers below)
        // lane holds A[row = lane&15][k = kh*32 + (lane>>4)*8 + j]
        float4 au[2], av[2];
#pragma unroll
        for (int p = 0; p < 2; ++p) {
            const float* srcp = edge_attr + (size_t)(ebase + c4) * 64 + p * 32 + (g << 3);
            au[p] = *(const float4*)srcp;
            av[p] = *(const float4*)(srcp + 4);
        }

        // ---- issue ALL 16 K/Q gathers now; they land during the MFMA phase
        float kv[16], qv[16];
#pragma unroll
        for (int r = 0; r < 16; ++r) {
            kv[r] = Kn[se[r] * 64 + lane];
            qv[r] = Qn[de[r] * 64 + lane];
        }

        // ---- build bf16 hi/lo A fragments
        short8 ah[2], al[2];
#pragma unroll
        for (int p = 0; p < 2; ++p) {
            const float xv[8] = {au[p].x, au[p].y, au[p].z, au[p].w,
                                 av[p].x, av[p].y, av[p].z, av[p].w};
#pragma unroll
            for (int j = 0; j < 8; ++j) {
                const short hb = f2bf(xv[j]);
                ah[p][j] = hb;
                al[p][j] = f2bf(xv[j] - bf2f(hb));
            }
        }

        // ---- MFMA: acc[ct] = E[16 rows][ct*16..+15]  (3-product bf16 split)
        f32x4 acc[8] = {};
#pragma unroll
        for (int kh = 0; kh < 2; ++kh) {
#pragma unroll
            for (int ct = 0; ct < 8; ++ct) {
                const short8 bh = Bhi[(ct * 2 + kh) * 64 + lane];
                const short8 bl = Blo[(ct * 2 + kh) * 64 + lane];
                acc[ct] = __builtin_amdgcn_mfma_f32_16x16x32_bf16(ah[kh], bh, acc[ct], 0, 0, 0);
                acc[ct] = __builtin_amdgcn_mfma_f32_16x16x32_bf16(al[kh], bh, acc[ct], 0, 0, 0);
                acc[ct] = __builtin_amdgcn_mfma_f32_16x16x32_bf16(ah[kh], bl, acc[ct], 0, 0, 0);
            }
        }

        // ---- score phase: 4 fenced quarters (R2-proven structure)
#pragma unroll
        for (int q = 0; q < 4; ++q) {
            if (g == q) {
#pragma unroll
                for (int ct = 0; ct < 8; ++ct) {
                    const int col = (ct << 4) + c4;
                    const float b = bEs[col];
                    f32x4 vq = acc[ct];
                    vq[0] += b; vq[1] += b; vq[2] += b; vq[3] += b;
                    *(f32x4*)(Ebuf_w + col * 4) = vq;   // E^T[col][rr]
                }
            }
            __asm__ volatile("s_waitcnt lgkmcnt(0)" ::: "memory");
            __builtin_amdgcn_sched_barrier(0);
#pragma unroll
            for (int rr = 0; rr < 4; ++rr) {
                const int e = ebase + q * 4 + rr;
                const float kq = kv[q * 4 + rr] + qv[q * 4 + rr];
                const float ew = Ebuf_w[h16k * 4 + rr];
                const float eb = Ebuf_w[(h16k + 8) * 4 + rr];
                float sc = kq * ew;
                sc = copysignf(sqrtf(fabsf(sc)), sc) + eb;  // signed sqrt
                wE_out[(size_t)e * 64 + lane] = sc;

                float pp = sc * Aws[kk * 8 + h];
                pp += __shfl_xor(pp, 1);
                pp += __shfl_xor(pp, 2);
                pp += __shfl_xor(pp, 4);
                pp = fminf(fmaxf(pp, -CLAMP_V), CLAMP_V);
                const float ex = __expf(pp);
                if (kk == 0) unsafeAtomicAdd(&denom[de[q * 4 + rr] * 8 + h], ex);
            }
            __builtin_amdgcn_sched_barrier(0);
        }
    }
}

// ---------------- Kernel 3: scatter wV (R2-exact, proven) ----------------
__global__ __launch_bounds__(256) void scatter_kernel(
    const int* __restrict__ src_idx, const int* __restrict__ dst_idx,
    const float* __restrict__ Vn, const float* __restrict__ wE_out,
    const float* __restrict__ denom,
    const float* __restrict__ Aw, const float* __restrict__ VeRow,
    float* __restrict__ wV_out)
{
    __shared__ float VeL[512];
    __shared__ float AwL[64];
    const int t = threadIdx.x;
    if (t < 64) AwL[t] = Aw[t];
    for (int i = t; i < 512; i += 256) VeL[i] = VeRow[i];
    __syncthreads();

    const int wave = t >> 6;
    const int lane = t & 63;
    const int h = lane >> 3;
    const int kk = lane & 7;
    const int totalWaves = gridDim.x * 4;

    for (int e = blockIdx.x * 4 + wave; e < N_EDGES; e += totalWaves) {
        const int s = src_idx[e];
        const int d = dst_idx[e];
        const float et = wE_out[(size_t)e * 64 + lane];

        float p = et * AwL[kk * 8 + h];
        p += __shfl_xor(p, 1);
        p += __shfl_xor(p, 2);
        p += __shfl_xor(p, 4);
        p = fminf(fmaxf(p, -CLAMP_V), CLAMP_V);
        const float ex = __expf(p);
        const float dn = denom[(size_t)d * 8 + h];
        const float attn = ex / (dn + 1e-16f);

        const float vv = Vn[(size_t)s * 64 + lane];
        float rsum = 0.f;
#pragma unroll
        for (int dd = 0; dd < 8; ++dd) {
            const float etd = __shfl(et, (lane & 56) + dd);
            rsum += etd * VeL[dd * 64 + lane];
        }
        unsafeAtomicAdd(&wV_out[(size_t)d * 64 + lane], attn * (vv + rsum));
    }
}

extern "C" void kernel_launch(void* const* d_in, const int* in_sizes, int n_in,
                              void* d_out, int out_size, void* d_ws, size_t ws_size,
                              hipStream_t stream) {
    const float* x         = (const float*)d_in[0];
    const float* edge_attr = (const float*)d_in[1];
    const int*   ei        = (const int*)  d_in[2];
    const float* WQ = (const float*)d_in[3];
    const float* bQ = (const float*)d_in[4];
    const float* WK = (const float*)d_in[5];
    const float* bK = (const float*)d_in[6];
    const float* WE = (const float*)d_in[7];
    const float* bE = (const float*)d_in[8];
    const float* WV = (const float*)d_in[9];
    const float* bV = (const float*)d_in[10];
    const float* Aw = (const float*)d_in[11];
    const float* VeRow = (const float*)d_in[12];

    float* out    = (float*)d_out;
    float* wV_out = out;                        // 50000*64
    float* wE_out = out + (size_t)N_NODES * 64; // 800000*64

    float* ws    = (float*)d_ws;
    float* Q     = ws;
    float* K     = ws + 3200000;
    float* V     = ws + 6400000;
    float* denom = ws + 9600000;

    const int* src_idx = ei;
    const int* dst_idx = ei + N_EDGES;

    hipMemsetAsync(wV_out, 0, (size_t)N_NODES * 64 * sizeof(float), stream);
    hipMemsetAsync(denom, 0, (size_t)N_NODES * 8 * sizeof(float), stream);

    qkv_kernel<<<3125, 256, 0, stream>>>(x, WQ, bQ, WK, bK, WV, bV, Q, K, V);
    edge_kernel<<<768, 256, 0, stream>>>(edge_attr, src_idx, dst_idx, WE, bE, Aw,
                                         Q, K, wE_out, denom);
    scatter_kernel<<<2048, 256, 0, stream>>>(src_idx, dst_idx, V, wE_out, denom,
                                             Aw, VeRow, wV_out);
}

// Round 5
// 335.686 us; speedup vs baseline: 2.3314x; 1.1749x over previous
//
#include <hip/hip_runtime.h>
#include <hip/hip_bf16.h>
#include <math.h>

#define N_NODES 50000
#define N_EDGES 800000
#define CLAMP_V 5.0f

typedef short short8 __attribute__((ext_vector_type(8)));
typedef float f32x4  __attribute__((ext_vector_type(4)));

static __device__ inline short f2bf(float x) {
    __hip_bfloat16 h = __float2bfloat16(x);   // RNE
    return __builtin_bit_cast(short, h);
}
static __device__ inline float bf2f(short s) {
    unsigned u = ((unsigned)(unsigned short)s) << 16;
    return __builtin_bit_cast(float, u);
}

// ---------------- Kernel 1: Q/K/V node projections (unchanged, proven) ----------------
__global__ __launch_bounds__(256) void qkv_kernel(
    const float* __restrict__ x,
    const float* __restrict__ WQ, const float* __restrict__ bQ,
    const float* __restrict__ WK, const float* __restrict__ bK,
    const float* __restrict__ WV, const float* __restrict__ bV,
    float* __restrict__ Q, float* __restrict__ K, float* __restrict__ V)
{
    const int t = threadIdx.x;
    const int c = t & 63;
    const int nl = t >> 6;
    const int base = blockIdx.x * 16;

    float accQ[4], accK[4], accV[4];
    int nodes[4];
#pragma unroll
    for (int j = 0; j < 4; ++j) {
        nodes[j] = base + j * 4 + nl;
        accQ[j] = bQ[c]; accK[j] = bK[c]; accV[j] = bV[c];
    }
    for (int k = 0; k < 64; ++k) {
        const float wq = WQ[k * 64 + c];
        const float wk = WK[k * 64 + c];
        const float wv = WV[k * 64 + c];
#pragma unroll
        for (int j = 0; j < 4; ++j) {
            const float xv = x[nodes[j] * 64 + k];
            accQ[j] += xv * wq;
            accK[j] += xv * wk;
            accV[j] += xv * wv;
        }
    }
#pragma unroll
    for (int j = 0; j < 4; ++j) {
        const int n = nodes[j];
        Q[n * 64 + c] = accQ[j];
        K[n * 64 + c] = accK[j];
        V[n * 64 + c] = accV[j];
    }
}

// ---------------- Kernel 2: fused E-GEMM + score + denom + numerator ----------------
// R4's proven fenced structure. New: per-edge numerator accumulation
//   wV_num[d] += ex * (V[src] + e_t @ VeRow)
// with fire-and-forget atomics (normalization deferred to finalize_kernel,
// valid since denom[d] is constant per destination node).
__global__ __launch_bounds__(256, 3) void edge_kernel(
    const float* __restrict__ edge_attr,
    const int* __restrict__ src_idx, const int* __restrict__ dst_idx,
    const float* __restrict__ WE, const float* __restrict__ bE,
    const float* __restrict__ Aw,
    const float* __restrict__ Qn, const float* __restrict__ Kn,
    const float* __restrict__ Vn, const float* __restrict__ VeRow,
    float* __restrict__ wE_out, float* __restrict__ denom,
    float* __restrict__ wV_num)
{
    // [0,16K)=B_hi  [16K,32K)=B_lo  [32K,40K)=E transpose buf (2KB/wave)
    __shared__ __align__(16) char raw[40960];
    __shared__ float bEs[128];
    __shared__ float Aws[64];
    __shared__ float VeL[512];

    short8* Bhi = (short8*)raw;                  // [(ct*2+kh)*64 + lane]
    short8* Blo = (short8*)(raw + 16384);

    const int t = threadIdx.x;
    const int wave = t >> 6;
    const int lane = t & 63;

    // ---- init: bf16 hi/lo B-fragments from global WE
    short* BhiE = (short*)raw;
    short* BloE = (short*)(raw + 16384);
    for (int i = t; i < 8192; i += 256) {
        const int j  = i & 7;
        const int ln = (i >> 3) & 63;
        const int kh = (i >> 9) & 1;
        const int ct = i >> 10;
        const int k   = kh * 32 + ((ln >> 4) << 3) + j;
        const int col = (ct << 4) + (ln & 15);
        const float w = WE[k * 128 + col];
        const short hb = f2bf(w);
        BhiE[i] = hb;
        BloE[i] = f2bf(w - bf2f(hb));
    }
    if (t < 128) bEs[t] = bE[t];
    if (t < 64)  Aws[t] = Aw[t];
    for (int i = t; i < 512; i += 256) VeL[i] = VeRow[i];
    __syncthreads();

    float* Ebuf_w = (float*)(raw + 32768 + wave * 2048);  // [col*4 + rr]

    const int h    = lane >> 3;
    const int kk   = lane & 7;
    const int g    = lane >> 4;
    const int c4   = lane & 15;
    const int h16k = (h << 4) + kk;

    for (int it = blockIdx.x; it < 12500; it += gridDim.x) {
        const int ebase = __builtin_amdgcn_readfirstlane(it * 64 + wave * 16);

        // ---- scalar index loads for this wave's 16 edges
        int se[16], de[16];
#pragma unroll
        for (int r = 0; r < 16; ++r) {
            se[r] = src_idx[ebase + r];
            de[r] = dst_idx[ebase + r];
        }

        // ---- A fragment loads FIRST (so MFMA's vmcnt wait doesn't drain gathers)
        float4 au[2], av[2];
#pragma unroll
        for (int p = 0; p < 2; ++p) {
            const float* srcp = edge_attr + (size_t)(ebase + c4) * 64 + p * 32 + (g << 3);
            au[p] = *(const float4*)srcp;
            av[p] = *(const float4*)(srcp + 4);
        }

        // ---- issue ALL K/Q/V gathers now; they land during the MFMA phase
        float kv[16], qv[16], vv[16];
#pragma unroll
        for (int r = 0; r < 16; ++r) {
            kv[r] = Kn[se[r] * 64 + lane];
            qv[r] = Qn[de[r] * 64 + lane];
            vv[r] = Vn[se[r] * 64 + lane];
        }

        // ---- build bf16 hi/lo A fragments
        short8 ah[2], al[2];
#pragma unroll
        for (int p = 0; p < 2; ++p) {
            const float xv[8] = {au[p].x, au[p].y, au[p].z, au[p].w,
                                 av[p].x, av[p].y, av[p].z, av[p].w};
#pragma unroll
            for (int j = 0; j < 8; ++j) {
                const short hb = f2bf(xv[j]);
                ah[p][j] = hb;
                al[p][j] = f2bf(xv[j] - bf2f(hb));
            }
        }

        // ---- MFMA: acc[ct] = E[16 rows][ct*16..+15]  (3-product bf16 split)
        f32x4 acc[8] = {};
#pragma unroll
        for (int kh = 0; kh < 2; ++kh) {
#pragma unroll
            for (int ct = 0; ct < 8; ++ct) {
                const short8 bh = Bhi[(ct * 2 + kh) * 64 + lane];
                const short8 bl = Blo[(ct * 2 + kh) * 64 + lane];
                acc[ct] = __builtin_amdgcn_mfma_f32_16x16x32_bf16(ah[kh], bh, acc[ct], 0, 0, 0);
                acc[ct] = __builtin_amdgcn_mfma_f32_16x16x32_bf16(al[kh], bh, acc[ct], 0, 0, 0);
                acc[ct] = __builtin_amdgcn_mfma_f32_16x16x32_bf16(ah[kh], bl, acc[ct], 0, 0, 0);
            }
        }

        // ---- score phase: 4 fenced quarters (proven structure)
#pragma unroll
        for (int q = 0; q < 4; ++q) {
            if (g == q) {
#pragma unroll
                for (int ct = 0; ct < 8; ++ct) {
                    const int col = (ct << 4) + c4;
                    const float b = bEs[col];
                    f32x4 vq = acc[ct];
                    vq[0] += b; vq[1] += b; vq[2] += b; vq[3] += b;
                    *(f32x4*)(Ebuf_w + col * 4) = vq;   // E^T[col][rr]
                }
            }
            __asm__ volatile("s_waitcnt lgkmcnt(0)" ::: "memory");
            __builtin_amdgcn_sched_barrier(0);
#pragma unroll
            for (int rr = 0; rr < 4; ++rr) {
                const int e = ebase + q * 4 + rr;
                const int d = de[q * 4 + rr];
                const float kq = kv[q * 4 + rr] + qv[q * 4 + rr];
                const float ew = Ebuf_w[h16k * 4 + rr];
                const float eb = Ebuf_w[(h16k + 8) * 4 + rr];
                float sc = kq * ew;
                sc = copysignf(sqrtf(fabsf(sc)), sc) + eb;  // signed sqrt
                wE_out[(size_t)e * 64 + lane] = sc;

                float pp = sc * Aws[kk * 8 + h];
                pp += __shfl_xor(pp, 1);
                pp += __shfl_xor(pp, 2);
                pp += __shfl_xor(pp, 4);
                pp = fminf(fmaxf(pp, -CLAMP_V), CLAMP_V);
                const float ex = __expf(pp);
                if (kk == 0) unsafeAtomicAdd(&denom[d * 8 + h], ex);

                // ---- numerator: ex * (V[src] + e_t @ VeRow), deferred norm
                float rsum = 0.f;
#pragma unroll
                for (int dd = 0; dd < 8; ++dd) {
                    const float etd = __shfl(sc, (lane & 56) + dd);  // e_t[h,dd]
                    rsum += etd * VeL[dd * 64 + lane];               // VeRow[dd,h,kk]
                }
                unsafeAtomicAdd(&wV_num[(size_t)d * 64 + lane],
                                ex * (vv[q * 4 + rr] + rsum));
            }
            __builtin_amdgcn_sched_barrier(0);
        }
    }
}

// ---------------- Kernel 3: finalize — wV = numer / denom ----------------
__global__ __launch_bounds__(256) void finalize_kernel(
    const float* __restrict__ denom, float* __restrict__ wV)
{
    const int i = blockIdx.x * 256 + threadIdx.x;   // 12500 blocks * 256 = 3.2M
    const int n = i >> 6;
    const int h = (i >> 3) & 7;
    const float dn = denom[n * 8 + h] + 1e-16f;
    wV[i] = wV[i] / dn;
}

extern "C" void kernel_launch(void* const* d_in, const int* in_sizes, int n_in,
                              void* d_out, int out_size, void* d_ws, size_t ws_size,
                              hipStream_t stream) {
    const float* x         = (const float*)d_in[0];
    const float* edge_attr = (const float*)d_in[1];
    const int*   ei        = (const int*)  d_in[2];
    const float* WQ = (const float*)d_in[3];
    const float* bQ = (const float*)d_in[4];
    const float* WK = (const float*)d_in[5];
    const float* bK = (const float*)d_in[6];
    const float* WE = (const float*)d_in[7];
    const float* bE = (const float*)d_in[8];
    const float* WV = (const float*)d_in[9];
    const float* bV = (const float*)d_in[10];
    const float* Aw = (const float*)d_in[11];
    const float* VeRow = (const float*)d_in[12];

    float* out    = (float*)d_out;
    float* wV_out = out;                        // 50000*64 (numerator, then final)
    float* wE_out = out + (size_t)N_NODES * 64; // 800000*64

    float* ws    = (float*)d_ws;
    float* Q     = ws;
    float* K     = ws + 3200000;
    float* V     = ws + 6400000;
    float* denom = ws + 9600000;

    const int* src_idx = ei;
    const int* dst_idx = ei + N_EDGES;

    hipMemsetAsync(wV_out, 0, (size_t)N_NODES * 64 * sizeof(float), stream);
    hipMemsetAsync(denom, 0, (size_t)N_NODES * 8 * sizeof(float), stream);

    qkv_kernel<<<3125, 256, 0, stream>>>(x, WQ, bQ, WK, bK, WV, bV, Q, K, V);
    edge_kernel<<<768, 256, 0, stream>>>(edge_attr, src_idx, dst_idx, WE, bE, Aw,
                                         Q, K, V, VeRow, wE_out, denom, wV_out);
    finalize_kernel<<<12500, 256, 0, stream>>>(denom, wV_out);
}